// Round 4
// baseline (344.197 us; speedup 1.0000x reference)
//
#include <hip/hip_runtime.h>
#include <math.h>

#define D 128
#define GRAPHS 64

typedef __attribute__((ext_vector_type(8))) short bf16x8;
typedef __attribute__((ext_vector_type(4))) float f32x4;

union U4H8 { uint4 u; bf16x8 h; };

__device__ __forceinline__ unsigned short f2bf(float f) {   // RNE
  union { float f; unsigned u; } v; v.f = f;
  unsigned r = v.u + 0x7fffu + ((v.u >> 16) & 1u);
  return (unsigned short)(r >> 16);
}
__device__ __forceinline__ unsigned asu(float f) {
  union { float f; unsigned u; } v; v.f = f; return v.u;
}
__device__ __forceinline__ float asf(unsigned u) {
  union { unsigned u; float f; } v; v.u = u; return v.f;
}

// ---------------------------------------------------------------------------
// Gram: one kernel, no workspace. grid = GRAPHS blocks x 1024 thr (16 waves).
// 4 wave-groups x 4 waves; group kg accumulates X^T X over k-slice kg*L/4..,
// fp32 accs; 2-pass LDS atomic reduce (reusing staging LDS) -> bf16 Gram.
// Staging LDS is fragment-ordered: frag reads are lane*16B contiguous.
// ---------------------------------------------------------------------------
__global__ __launch_bounds__(1024) void gram_kernel(
    const float* __restrict__ feats, unsigned short* __restrict__ gram, int L) {
  const int g = blockIdx.x;
  const float* __restrict__ X = feats + (size_t)g * L * D;

  __shared__ __align__(16) unsigned char smem[32768];
  unsigned short* sXf = (unsigned short*)smem;  // [(kg*8+t)*64+lane]*8  (bf16)
  float* sR = (float*)smem;                     // [64][128] reduce buffer

  const int tid = threadIdx.x;
  const int wv = tid >> 6, lane = tid & 63;
  const int kg = wv >> 2, wg = wv & 3;
  const int quad = lane >> 4, ln = lane & 15;
  const int tgrp = tid & 255;  // thread index within wave-group

  f32x4 acc[2][8];
#pragma unroll
  for (int rt = 0; rt < 2; ++rt)
#pragma unroll
    for (int ct = 0; ct < 8; ++ct) acc[rt][ct] = (f32x4)(0.f);

  const int Lq = L >> 2;
  for (int it = 0; it < Lq; it += 32) {
    const int k0 = kg * Lq + it;
    __syncthreads();
    // stage+transpose this group's 32xk x 128d chunk into frag order
#pragma unroll
    for (int v = 0; v < 2; ++v) {
      int idx = tgrp + v * 256;              // 512 pair-tasks per group
      int k2 = idx & 15, d4 = idx >> 4;
      int k = k2 * 2, dd = d4 * 4;
      float4 r0 = *(const float4*)(X + (size_t)(k0 + k) * D + dd);
      float4 r1 = *(const float4*)(X + (size_t)(k0 + k + 1) * D + dd);
      const float* p0 = (const float*)&r0;
      const float* p1 = (const float*)&r1;
      int qs = k >> 3, j = k & 7;
#pragma unroll
      for (int i = 0; i < 4; ++i) {
        int d = dd + i;
        int t = d >> 4, lnw = d & 15;
        unsigned pack = (unsigned)f2bf(p0[i]) | ((unsigned)f2bf(p1[i]) << 16);
        *(unsigned*)&sXf[((kg * 8 + t) * 64 + qs * 16 + lnw) * 8 + j] = pack;
      }
    }
    __syncthreads();
    bf16x8 bfr[8];
#pragma unroll
    for (int ct = 0; ct < 8; ++ct)
      bfr[ct] = *(const bf16x8*)&sXf[((kg * 8 + ct) * 64 + lane) * 8];
#pragma unroll
    for (int rt = 0; rt < 2; ++rt)
#pragma unroll
      for (int ct = 0; ct < 8; ++ct)
        acc[rt][ct] = __builtin_amdgcn_mfma_f32_16x16x32_bf16(
            bfr[2 * wg + rt], bfr[ct], acc[rt][ct], 0, 0, 0);
  }

  // 2-pass cross-group reduce (rows 0-63, then 64-127), reusing smem as fp32
  for (int p = 0; p < 2; ++p) {
    __syncthreads();
    *(float4*)&sR[tid * 8] = make_float4(0.f, 0.f, 0.f, 0.f);
    *(float4*)&sR[tid * 8 + 4] = make_float4(0.f, 0.f, 0.f, 0.f);
    __syncthreads();
    if ((wg >> 1) == p) {
#pragma unroll
      for (int rt = 0; rt < 2; ++rt)
#pragma unroll
        for (int ct = 0; ct < 8; ++ct)
#pragma unroll
          for (int r = 0; r < 4; ++r) {
            int row = 32 * wg + 16 * rt + quad * 4 + r;
            atomicAdd(&sR[(row - p * 64) * 128 + 16 * ct + ln], acc[rt][ct][r]);
          }
    }
    __syncthreads();
    int rl = tid >> 4, c0 = (tid & 15) * 8;
    float4 a = *(float4*)&sR[rl * 128 + c0];
    float4 b = *(float4*)&sR[rl * 128 + c0 + 4];
    uint4 o;
    o.x = (unsigned)f2bf(a.x) | ((unsigned)f2bf(a.y) << 16);
    o.y = (unsigned)f2bf(a.z) | ((unsigned)f2bf(a.w) << 16);
    o.z = (unsigned)f2bf(b.x) | ((unsigned)f2bf(b.y) << 16);
    o.w = (unsigned)f2bf(b.z) | ((unsigned)f2bf(b.w) << 16);
    *(uint4*)&gram[(size_t)g * (D * D) + (size_t)(p * 64 + rl) * D + c0] = o;
  }
}

// ---------------------------------------------------------------------------
// W2: w2bf[p][d] = bf16(w[p][d]^2).  grid = D*D/256 = 64.
// ---------------------------------------------------------------------------
__global__ __launch_bounds__(256) void w2_kernel(
    const float* __restrict__ w, unsigned short* __restrict__ w2) {
  int idx = blockIdx.x * 256 + threadIdx.x;
  float v = w[idx];
  w2[idx] = f2bf(v * v);
}

// ---------------------------------------------------------------------------
// Fused main. One block = 32 rows of graph gi; 4 waves split 128 out-cols.
// All LDS tiles in MFMA-fragment-linear order -> conflict-free frag reads.
//  phase1: V2 = A * Gram[gi^1]      phase2: (A.V2, A.A, V2.V2) x W2^T
//  epilogue: out = num * rsq(max(s1*s2, 1e-16))  ( == num/max(sqrt(s1 s2),1e-8) )
// ---------------------------------------------------------------------------
__global__ __launch_bounds__(256) void fused_kernel2(
    const float* __restrict__ feats, const unsigned short* __restrict__ gram,
    const unsigned short* __restrict__ w2, float* __restrict__ out, int L) {
  const int tiles = L / 32;
  const int gi = blockIdx.x / tiles;
  const int row0 = (blockIdx.x - gi * tiles) * 32;
  const float* __restrict__ A = feats + ((size_t)gi * L + row0) * D;
  const unsigned short* __restrict__ G = gram + (size_t)(gi ^ 1) * (D * D);
  float* __restrict__ O = out + ((size_t)gi * L + row0) * D;

  __shared__ __align__(16) unsigned short sAf[4096];   // ((kc*2+rt)*64+lane)*8
  __shared__ __align__(16) unsigned short sVf[4096];
  __shared__ __align__(16) unsigned short sBf[16384];  // ((kc*8+tb)*64+lane)*8

  const int tid = threadIdx.x;
  const int wv = tid >> 6, lane = tid & 63, quad = lane >> 4, ln = lane & 15;

  // stage A (fp32 -> bf16, frag order): 1024 float4 tasks, 4/thread
#pragma unroll
  for (int v = 0; v < 4; ++v) {
    int idx = tid + v * 256;
    int r = idx >> 5, c4 = idx & 31;
    float4 t = *(const float4*)(A + (size_t)r * D + c4 * 4);
    int kc = c4 >> 3, qd = (c4 & 7) >> 1, j0 = (c4 & 1) * 4;
    int rt = r >> 4, lnw = r & 15;
    uint2 pk;
    pk.x = (unsigned)f2bf(t.x) | ((unsigned)f2bf(t.y) << 16);
    pk.y = (unsigned)f2bf(t.z) | ((unsigned)f2bf(t.w) << 16);
    *(uint2*)&sAf[((kc * 2 + rt) * 64 + qd * 16 + lnw) * 8 + j0] = pk;
  }
  // stage Gram (bf16, frag order): 2048 uint4 tasks, 8/thread
#pragma unroll
  for (int v = 0; v < 8; ++v) {
    int idx = tid + v * 256;
    int r = idx >> 4, c16 = idx & 15;
    uint4 t = *(const uint4*)(G + (size_t)r * D + c16 * 8);
    int kc = c16 >> 2, qd = c16 & 3, tb = r >> 4, lnw = r & 15;
    *(uint4*)&sBf[((kc * 8 + tb) * 64 + qd * 16 + lnw) * 8] = t;
  }
  __syncthreads();

  // ---- phase 1: V2 = A * Gram ----
  f32x4 acc[2][2];
#pragma unroll
  for (int rt = 0; rt < 2; ++rt)
#pragma unroll
    for (int ct = 0; ct < 2; ++ct) acc[rt][ct] = (f32x4)(0.f);
#pragma unroll
  for (int kc = 0; kc < 4; ++kc) {
    bf16x8 af[2], bfr[2];
#pragma unroll
    for (int rt = 0; rt < 2; ++rt)
      af[rt] = *(const bf16x8*)&sAf[((kc * 2 + rt) * 64 + lane) * 8];
#pragma unroll
    for (int ct = 0; ct < 2; ++ct)
      bfr[ct] = *(const bf16x8*)&sBf[((kc * 8 + 2 * wv + ct) * 64 + lane) * 8];
#pragma unroll
    for (int rt = 0; rt < 2; ++rt)
#pragma unroll
      for (int ct = 0; ct < 2; ++ct)
        acc[rt][ct] = __builtin_amdgcn_mfma_f32_16x16x32_bf16(
            af[rt], bfr[ct], acc[rt][ct], 0, 0, 0);
  }
  // park V2 (C-layout -> A-frag order), bf16 RNE
#pragma unroll
  for (int rt = 0; rt < 2; ++rt)
#pragma unroll
    for (int ct = 0; ct < 2; ++ct)
#pragma unroll
      for (int r = 0; r < 4; ++r)
        sVf[((wv * 2 + rt) * 64 + (2 * ct + (ln >> 3)) * 16 + quad * 4 + r) * 8 +
            (ln & 7)] = f2bf(acc[rt][ct][r]);
  __syncthreads();

  // stage W2 into sBf (frag order)
#pragma unroll
  for (int v = 0; v < 8; ++v) {
    int idx = tid + v * 256;
    int r = idx >> 4, c16 = idx & 15;
    uint4 t = *(const uint4*)(w2 + (size_t)r * D + c16 * 8);
    int kc = c16 >> 2, qd = c16 & 3, tb = r >> 4, lnw = r & 15;
    *(uint4*)&sBf[((kc * 8 + tb) * 64 + qd * 16 + lnw) * 8] = t;
  }
  __syncthreads();

  // ---- phase 2: three GEMMs vs W2 ----
  f32x4 an[2][2], s1[2][2], s2[2][2];
#pragma unroll
  for (int rt = 0; rt < 2; ++rt)
#pragma unroll
    for (int ct = 0; ct < 2; ++ct) {
      an[rt][ct] = (f32x4)(0.f);
      s1[rt][ct] = (f32x4)(0.f);
      s2[rt][ct] = (f32x4)(0.f);
    }
#pragma unroll
  for (int dc = 0; dc < 4; ++dc) {
    U4H8 fx2[2], faa[2], fvv[2];
#pragma unroll
    for (int rt = 0; rt < 2; ++rt) {
      uint4 ua = *(const uint4*)&sAf[((dc * 2 + rt) * 64 + lane) * 8];
      uint4 uv = *(const uint4*)&sVf[((dc * 2 + rt) * 64 + lane) * 8];
      const unsigned* uap = &ua.x;
      const unsigned* uvp = &uv.x;
#pragma unroll
      for (int w = 0; w < 4; ++w) {
        float a0 = asf(uap[w] << 16), a1 = asf(uap[w] & 0xFFFF0000u);
        float v0 = asf(uvp[w] << 16), v1 = asf(uvp[w] & 0xFFFF0000u);
        (&fx2[rt].u.x)[w] =
            __builtin_amdgcn_perm(asu(a1 * v1), asu(a0 * v0), 0x07060302u);
        (&faa[rt].u.x)[w] =
            __builtin_amdgcn_perm(asu(a1 * a1), asu(a0 * a0), 0x07060302u);
        (&fvv[rt].u.x)[w] =
            __builtin_amdgcn_perm(asu(v1 * v1), asu(v0 * v0), 0x07060302u);
      }
    }
    bf16x8 wf[2];
#pragma unroll
    for (int ct = 0; ct < 2; ++ct)
      wf[ct] = *(const bf16x8*)&sBf[((dc * 8 + 2 * wv + ct) * 64 + lane) * 8];
#pragma unroll
    for (int rt = 0; rt < 2; ++rt)
#pragma unroll
      for (int ct = 0; ct < 2; ++ct) {
        an[rt][ct] = __builtin_amdgcn_mfma_f32_16x16x32_bf16(
            fx2[rt].h, wf[ct], an[rt][ct], 0, 0, 0);
        s1[rt][ct] = __builtin_amdgcn_mfma_f32_16x16x32_bf16(
            faa[rt].h, wf[ct], s1[rt][ct], 0, 0, 0);
        s2[rt][ct] = __builtin_amdgcn_mfma_f32_16x16x32_bf16(
            fvv[rt].h, wf[ct], s2[rt][ct], 0, 0, 0);
      }
  }

  // ---- epilogue: num * rsq(max(s1*s2, 1e-16)) ----
#pragma unroll
  for (int rt = 0; rt < 2; ++rt)
#pragma unroll
    for (int ct = 0; ct < 2; ++ct)
#pragma unroll
      for (int r = 0; r < 4; ++r) {
        float t = fmaxf(s1[rt][ct][r] * s2[rt][ct][r], 1e-16f);
        O[(size_t)(16 * rt + quad * 4 + r) * D + 32 * wv + 16 * ct + ln] =
            an[rt][ct][r] * __builtin_amdgcn_rsqf(t);
      }
}

extern "C" void kernel_launch(void* const* d_in, const int* in_sizes, int n_in,
                              void* d_out, int out_size, void* d_ws, size_t ws_size,
                              hipStream_t stream) {
  const float* feats = (const float*)d_in[0];
  const float* w = (const float*)d_in[1];
  float* out = (float*)d_out;
  const int L = (in_sizes[0] / D) / GRAPHS;  // 2048

  unsigned short* gramBuf = (unsigned short*)d_ws;                 // 2 MiB
  unsigned short* w2Buf = gramBuf + (size_t)GRAPHS * D * D;        // 32 KiB

  hipLaunchKernelGGL(w2_kernel, dim3(D * D / 256), dim3(256), 0, stream, w, w2Buf);
  hipLaunchKernelGGL(gram_kernel, dim3(GRAPHS), dim3(1024), 0, stream,
                     feats, gramBuf, L);
  hipLaunchKernelGGL(fused_kernel2, dim3(GRAPHS * (L / 32)), dim3(256), 0,
                     stream, feats, gramBuf, w2Buf, out, L);
}

// Round 5
// 232.738 us; speedup vs baseline: 1.4789x; 1.4789x over previous
//
#include <hip/hip_runtime.h>
#include <math.h>

#define D 128
#define GRAPHS 64
#define SLICES 8

typedef __attribute__((ext_vector_type(8))) short bf16x8;
typedef __attribute__((ext_vector_type(4))) float f32x4;

union U4H8 { uint4 u; bf16x8 h; };

__device__ __forceinline__ unsigned short f2bf(float f) {   // RNE
  union { float f; unsigned u; } v; v.f = f;
  unsigned r = v.u + 0x7fffu + ((v.u >> 16) & 1u);
  return (unsigned short)(r >> 16);
}
__device__ __forceinline__ unsigned asu(float f) {
  union { float f; unsigned u; } v; v.f = f; return v.u;
}
__device__ __forceinline__ float asf(unsigned u) {
  union { unsigned u; float f; } v; v.u = u; return v.f;
}

// ---------------------------------------------------------------------------
// zero gram fp32 accumulation buffer + compute w2 = bf16(w^2).
// grid = GRAPHS*D*D/4/256 = 1024 blocks.
// ---------------------------------------------------------------------------
__global__ __launch_bounds__(256) void zero_w2_kernel(
    const float* __restrict__ w, float* __restrict__ gramF,
    unsigned short* __restrict__ w2) {
  int idx = blockIdx.x * 256 + threadIdx.x;
  *(float4*)&gramF[(size_t)idx * 4] = make_float4(0.f, 0.f, 0.f, 0.f);
  if (idx < D * D) {
    float v = w[idx];
    w2[idx] = f2bf(v * v);
  }
}

// ---------------------------------------------------------------------------
// Gram partial accumulation: grid = GRAPHS*SLICES blocks x 256 thr (4 waves).
// Block (g, sl): accumulate X_sl^T X_sl over chunk=L/SLICES rows into fp32
// registers (wave wv: rows 32wv..32wv+31 x all 128 cols), then global
// atomicAdd into zeroed gramF[g]. Staging is frag-ordered bf16 (conflict-free
// ds_read_b128); next chunk register-prefetched.
// ---------------------------------------------------------------------------
__global__ __launch_bounds__(256, 2) void gram_atomic_kernel(
    const float* __restrict__ feats, float* __restrict__ gramF, int L) {
  const int g = blockIdx.x / SLICES;
  const int sl = blockIdx.x - g * SLICES;
  const int chunk = L / SLICES;  // 256
  const float* __restrict__ X = feats + ((size_t)g * L + (size_t)sl * chunk) * D;

  __shared__ __align__(16) unsigned short sXT[8 * 64 * 8];  // 8 KB, frag order
  const int tid = threadIdx.x;
  const int wv = tid >> 6, lane = tid & 63, quad = lane >> 4, ln = lane & 15;

  f32x4 acc[2][8];
#pragma unroll
  for (int rt = 0; rt < 2; ++rt)
#pragma unroll
    for (int ct = 0; ct < 8; ++ct) acc[rt][ct] = (f32x4)(0.f);

  // task decomposition: 512 pair-tasks (16 k-pairs x 32 d4), 2 per thread
  const int k2a = tid & 15, d4a = tid >> 4;             // task v=0
  const int k2b = (tid + 256) & 15, d4b = (tid + 256) >> 4;  // task v=1

  float4 pA0 = *(const float4*)(X + (size_t)(2 * k2a) * D + 4 * d4a);
  float4 pA1 = *(const float4*)(X + (size_t)(2 * k2a + 1) * D + 4 * d4a);
  float4 pB0 = *(const float4*)(X + (size_t)(2 * k2b) * D + 4 * d4b);
  float4 pB1 = *(const float4*)(X + (size_t)(2 * k2b + 1) * D + 4 * d4b);

  for (int it = 0; it < chunk; it += 32) {
    __syncthreads();
    // write prefetched chunk to LDS in frag order
    {
      const float* p0 = (const float*)&pA0;
      const float* p1 = (const float*)&pA1;
      int k = 2 * k2a, qs = k >> 3, j = k & 7;
#pragma unroll
      for (int i = 0; i < 4; ++i) {
        int d = 4 * d4a + i, t = d >> 4, lnw = d & 15;
        *(unsigned*)&sXT[(t * 64 + qs * 16 + lnw) * 8 + j] =
            (unsigned)f2bf(p0[i]) | ((unsigned)f2bf(p1[i]) << 16);
      }
      p0 = (const float*)&pB0;
      p1 = (const float*)&pB1;
      k = 2 * k2b; qs = k >> 3; j = k & 7;
#pragma unroll
      for (int i = 0; i < 4; ++i) {
        int d = 4 * d4b + i, t = d >> 4, lnw = d & 15;
        *(unsigned*)&sXT[(t * 64 + qs * 16 + lnw) * 8 + j] =
            (unsigned)f2bf(p0[i]) | ((unsigned)f2bf(p1[i]) << 16);
      }
    }
    __syncthreads();
    if (it + 32 < chunk) {  // prefetch next chunk while MFMAs run
      const float* Xn = X + (size_t)(it + 32) * D;
      pA0 = *(const float4*)(Xn + (size_t)(2 * k2a) * D + 4 * d4a);
      pA1 = *(const float4*)(Xn + (size_t)(2 * k2a + 1) * D + 4 * d4a);
      pB0 = *(const float4*)(Xn + (size_t)(2 * k2b) * D + 4 * d4b);
      pB1 = *(const float4*)(Xn + (size_t)(2 * k2b + 1) * D + 4 * d4b);
    }
    bf16x8 bfr[8];
#pragma unroll
    for (int ct = 0; ct < 8; ++ct)
      bfr[ct] = *(const bf16x8*)&sXT[(ct * 64 + lane) * 8];
#pragma unroll
    for (int rt = 0; rt < 2; ++rt)
#pragma unroll
      for (int ct = 0; ct < 8; ++ct)
        acc[rt][ct] = __builtin_amdgcn_mfma_f32_16x16x32_bf16(
            bfr[2 * wv + rt], bfr[ct], acc[rt][ct], 0, 0, 0);
  }

  float* GF = gramF + (size_t)g * (D * D);
#pragma unroll
  for (int rt = 0; rt < 2; ++rt)
#pragma unroll
    for (int ct = 0; ct < 8; ++ct)
#pragma unroll
      for (int r = 0; r < 4; ++r)
        atomicAdd(&GF[(size_t)(32 * wv + 16 * rt + quad * 4 + r) * D +
                      16 * ct + ln],
                  acc[rt][ct][r]);
}

// ---------------------------------------------------------------------------
// Convert gram fp32 -> bf16.  grid = GRAPHS*D*D/(8*256) = 512.
// ---------------------------------------------------------------------------
__global__ __launch_bounds__(256) void gram_convert_kernel(
    const float* __restrict__ gramF, unsigned short* __restrict__ gramBF) {
  int idx = blockIdx.x * 256 + threadIdx.x;
  const float* src = gramF + (size_t)idx * 8;
  float4 a = *(const float4*)src;
  float4 b = *(const float4*)(src + 4);
  uint4 o;
  o.x = (unsigned)f2bf(a.x) | ((unsigned)f2bf(a.y) << 16);
  o.y = (unsigned)f2bf(a.z) | ((unsigned)f2bf(a.w) << 16);
  o.z = (unsigned)f2bf(b.x) | ((unsigned)f2bf(b.y) << 16);
  o.w = (unsigned)f2bf(b.z) | ((unsigned)f2bf(b.w) << 16);
  *(uint4*)&gramBF[(size_t)idx * 8] = o;
}

// ---------------------------------------------------------------------------
// Fused main. Block = 512 thr (8 waves) = 128 rows of graph gi.
// Wave wv: rows [16wv,16wv+16) x ALL 128 cols -> phase-2 repack done ONCE per
// row (no per-column-wave redundancy). All LDS tiles frag-linear.
//  phase1: V2 = A*Gram[gi^1]; phase2: (A.V2, A.A, V2.V2) x W2^T;
//  epilogue: num * rsq(max(s1*s2,1e-16)).
// ---------------------------------------------------------------------------
__global__ __launch_bounds__(512, 2) void fused_kernel3(
    const float* __restrict__ feats, const unsigned short* __restrict__ gram,
    const unsigned short* __restrict__ w2, float* __restrict__ out, int L) {
  const int tiles = L >> 7;  // blocks per graph
  const int gi = blockIdx.x / tiles;
  const int row0 = (blockIdx.x - gi * tiles) << 7;
  const float* __restrict__ A = feats + ((size_t)gi * L + row0) * D;
  const unsigned short* __restrict__ G = gram + (size_t)(gi ^ 1) * (D * D);
  float* __restrict__ O = out + ((size_t)gi * L + row0) * D;

  __shared__ __align__(16) unsigned short sAf[16384];  // ((kc*8+rt)*64+lane)*8
  __shared__ __align__(16) unsigned short sVf[16384];
  __shared__ __align__(16) unsigned short sBf[16384];

  const int tid = threadIdx.x;
  const int wv = tid >> 6, lane = tid & 63, quad = lane >> 4, ln = lane & 15;

  // stage A (fp32 -> bf16, frag order): 4096 float4 tasks, 8/thread
#pragma unroll
  for (int v = 0; v < 8; ++v) {
    int idx = tid + v * 512;
    int r = idx >> 5, c4 = idx & 31;
    float4 t = *(const float4*)(A + (size_t)r * D + c4 * 4);
    int kc = c4 >> 3, qd = (c4 & 7) >> 1, j0 = (c4 & 1) * 4;
    int rt = r >> 4, lnw = r & 15;
    uint2 pk;
    pk.x = (unsigned)f2bf(t.x) | ((unsigned)f2bf(t.y) << 16);
    pk.y = (unsigned)f2bf(t.z) | ((unsigned)f2bf(t.w) << 16);
    *(uint2*)&sAf[((kc * 8 + rt) * 64 + qd * 16 + lnw) * 8 + j0] = pk;
  }
  // stage Gram (bf16 frag order): 2048 uint4 tasks, 4/thread
#pragma unroll
  for (int v = 0; v < 4; ++v) {
    int idx = tid + v * 512;
    int r = idx >> 4, c16 = idx & 15;
    uint4 t = *(const uint4*)(G + (size_t)r * D + c16 * 8);
    int kc = c16 >> 2, qd = c16 & 3, tb = r >> 4, lnw = r & 15;
    *(uint4*)&sBf[((kc * 8 + tb) * 64 + qd * 16 + lnw) * 8] = t;
  }
  __syncthreads();

  // ---- phase 1: V2 = A * Gram ----
  f32x4 acc1[8];
#pragma unroll
  for (int ct = 0; ct < 8; ++ct) acc1[ct] = (f32x4)(0.f);
#pragma unroll
  for (int kc = 0; kc < 4; ++kc) {
    bf16x8 af = *(const bf16x8*)&sAf[((kc * 8 + wv) * 64 + lane) * 8];
#pragma unroll
    for (int ct = 0; ct < 8; ++ct) {
      bf16x8 bfr = *(const bf16x8*)&sBf[((kc * 8 + ct) * 64 + lane) * 8];
      acc1[ct] = __builtin_amdgcn_mfma_f32_16x16x32_bf16(af, bfr, acc1[ct], 0, 0, 0);
    }
  }
  // park V2 (C-layout -> A-frag order), rows stay within this wave's tile
#pragma unroll
  for (int ct = 0; ct < 8; ++ct)
#pragma unroll
    for (int r = 0; r < 4; ++r) {
      int col = ct * 16 + ln;
      int kc_t = col >> 5, q_t = (col >> 3) & 3, j_t = col & 7;
      sVf[((kc_t * 8 + wv) * 64 + q_t * 16 + quad * 4 + r) * 8 + j_t] =
          f2bf(acc1[ct][r]);
    }
  __syncthreads();

  // stage W2 into sBf (frag order)
#pragma unroll
  for (int v = 0; v < 4; ++v) {
    int idx = tid + v * 512;
    int r = idx >> 4, c16 = idx & 15;
    uint4 t = *(const uint4*)(w2 + (size_t)r * D + c16 * 8);
    int kc = c16 >> 2, qd = c16 & 3, tb = r >> 4, lnw = r & 15;
    *(uint4*)&sBf[((kc * 8 + tb) * 64 + qd * 16 + lnw) * 8] = t;
  }
  __syncthreads();

  // ---- phase 2: three GEMMs vs W2 ----
  f32x4 an[8], s1[8], s2[8];
#pragma unroll
  for (int ct = 0; ct < 8; ++ct) {
    an[ct] = (f32x4)(0.f);
    s1[ct] = (f32x4)(0.f);
    s2[ct] = (f32x4)(0.f);
  }
#pragma unroll
  for (int dc = 0; dc < 4; ++dc) {
    uint4 ua = *(const uint4*)&sAf[((dc * 8 + wv) * 64 + lane) * 8];
    uint4 uv = *(const uint4*)&sVf[((dc * 8 + wv) * 64 + lane) * 8];
    U4H8 fx2, faa, fvv;
    const unsigned* uap = &ua.x;
    const unsigned* uvp = &uv.x;
#pragma unroll
    for (int w = 0; w < 4; ++w) {
      float a0 = asf(uap[w] << 16), a1 = asf(uap[w] & 0xFFFF0000u);
      float v0 = asf(uvp[w] << 16), v1 = asf(uvp[w] & 0xFFFF0000u);
      (&fx2.u.x)[w] = __builtin_amdgcn_perm(asu(a1 * v1), asu(a0 * v0), 0x07060302u);
      (&faa.u.x)[w] = __builtin_amdgcn_perm(asu(a1 * a1), asu(a0 * a0), 0x07060302u);
      (&fvv.u.x)[w] = __builtin_amdgcn_perm(asu(v1 * v1), asu(v0 * v0), 0x07060302u);
    }
#pragma unroll
    for (int ct = 0; ct < 8; ++ct) {
      bf16x8 wf = *(const bf16x8*)&sBf[((dc * 8 + ct) * 64 + lane) * 8];
      an[ct] = __builtin_amdgcn_mfma_f32_16x16x32_bf16(fx2.h, wf, an[ct], 0, 0, 0);
      s1[ct] = __builtin_amdgcn_mfma_f32_16x16x32_bf16(faa.h, wf, s1[ct], 0, 0, 0);
      s2[ct] = __builtin_amdgcn_mfma_f32_16x16x32_bf16(fvv.h, wf, s2[ct], 0, 0, 0);
    }
  }

  // ---- epilogue ----
#pragma unroll
  for (int ct = 0; ct < 8; ++ct)
#pragma unroll
    for (int r = 0; r < 4; ++r) {
      float t = fmaxf(s1[ct][r] * s2[ct][r], 1e-16f);
      O[(size_t)(wv * 16 + quad * 4 + r) * D + ct * 16 + ln] =
          an[ct][r] * __builtin_amdgcn_rsqf(t);
    }
}

extern "C" void kernel_launch(void* const* d_in, const int* in_sizes, int n_in,
                              void* d_out, int out_size, void* d_ws, size_t ws_size,
                              hipStream_t stream) {
  const float* feats = (const float*)d_in[0];
  const float* w = (const float*)d_in[1];
  float* out = (float*)d_out;
  const int L = (in_sizes[0] / D) / GRAPHS;  // 2048

  float* gramF = (float*)d_ws;                                        // 4 MiB
  unsigned short* gramBF = (unsigned short*)(gramF + (size_t)GRAPHS * D * D);  // 2 MiB
  unsigned short* w2Buf = gramBF + (size_t)GRAPHS * D * D;             // 32 KiB

  hipLaunchKernelGGL(zero_w2_kernel, dim3(GRAPHS * D * D / 4 / 256), dim3(256),
                     0, stream, w, gramF, w2Buf);
  hipLaunchKernelGGL(gram_atomic_kernel, dim3(GRAPHS * SLICES), dim3(256), 0,
                     stream, feats, gramF, L);
  hipLaunchKernelGGL(gram_convert_kernel, dim3(GRAPHS * D * D / (8 * 256)),
                     dim3(256), 0, stream, gramF, gramBF);
  hipLaunchKernelGGL(fused_kernel3, dim3(GRAPHS * (L >> 7)), dim3(512), 0,
                     stream, feats, gramBF, w2Buf, out, L);
}

// Round 6
// 218.496 us; speedup vs baseline: 1.5753x; 1.0652x over previous
//
#include <hip/hip_runtime.h>
#include <math.h>

#define D 128
#define GRAPHS 64

typedef __attribute__((ext_vector_type(8))) short bf16x8;
typedef __attribute__((ext_vector_type(4))) float f32x4;

union U4H8 { uint4 u; bf16x8 h; };

__device__ __forceinline__ unsigned short f2bf(float f) {   // RNE
  union { float f; unsigned u; } v; v.f = f;
  unsigned r = v.u + 0x7fffu + ((v.u >> 16) & 1u);
  return (unsigned short)(r >> 16);
}
__device__ __forceinline__ unsigned asu(float f) {
  union { float f; unsigned u; } v; v.f = f; return v.u;
}
__device__ __forceinline__ float asf(unsigned u) {
  union { unsigned u; float f; } v; v.u = u; return v.f;
}

// ---------------------------------------------------------------------------
// W2: w2bf[p][d] = bf16(w[p][d]^2).  grid = D*D/256 = 64.
// ---------------------------------------------------------------------------
__global__ __launch_bounds__(256) void w2_kernel(
    const float* __restrict__ w, unsigned short* __restrict__ w2) {
  int idx = blockIdx.x * 256 + threadIdx.x;
  float v = w[idx];
  w2[idx] = f2bf(v * v);
}

// ---------------------------------------------------------------------------
// Gram col-slab: grid = GRAPHS*4 = 256 blocks (1/CU) x 256 thr (4 waves).
// Block (g, cs): rows ALL 128 x cols [32cs, 32cs+32), K=2048 inside the block
// (fp32 register accumulation; no cross-block reduction, no atomics, no
// partials). Wave wv: rows [32wv,32wv+32) x 32 cols -> acc[2][2] (16 VGPRs).
// Staging frag-ordered bf16 (conflict-free ds_read_b128), register prefetch.
// ---------------------------------------------------------------------------
__global__ __launch_bounds__(256, 2) void gram_slab_kernel(
    const float* __restrict__ feats, unsigned short* __restrict__ gram, int L) {
  const int g = blockIdx.x >> 2;
  const int cs = blockIdx.x & 3;
  const float* __restrict__ X = feats + (size_t)g * L * D;

  __shared__ __align__(16) unsigned short sXT[8 * 64 * 8];  // 8 KB, frag order
  const int tid = threadIdx.x;
  const int wv = tid >> 6, lane = tid & 63, quad = lane >> 4, ln = lane & 15;

  f32x4 acc[2][2];
#pragma unroll
  for (int rt = 0; rt < 2; ++rt)
#pragma unroll
    for (int ct = 0; ct < 2; ++ct) acc[rt][ct] = (f32x4)(0.f);

  // 512 pair-tasks (16 k-pairs x 32 d4), 2 per thread
  const int k2a = tid & 15, d4a = tid >> 4;                  // task v=0
  const int k2b = (tid + 256) & 15, d4b = (tid + 256) >> 4;  // task v=1

  float4 pA0 = *(const float4*)(X + (size_t)(2 * k2a) * D + 4 * d4a);
  float4 pA1 = *(const float4*)(X + (size_t)(2 * k2a + 1) * D + 4 * d4a);
  float4 pB0 = *(const float4*)(X + (size_t)(2 * k2b) * D + 4 * d4b);
  float4 pB1 = *(const float4*)(X + (size_t)(2 * k2b + 1) * D + 4 * d4b);

  for (int it = 0; it < L; it += 32) {
    __syncthreads();
    {
      const float* p0 = (const float*)&pA0;
      const float* p1 = (const float*)&pA1;
      int k = 2 * k2a, qs = k >> 3, j = k & 7;
#pragma unroll
      for (int i = 0; i < 4; ++i) {
        int d = 4 * d4a + i, t = d >> 4, lnw = d & 15;
        *(unsigned*)&sXT[(t * 64 + qs * 16 + lnw) * 8 + j] =
            (unsigned)f2bf(p0[i]) | ((unsigned)f2bf(p1[i]) << 16);
      }
      p0 = (const float*)&pB0;
      p1 = (const float*)&pB1;
      k = 2 * k2b; qs = k >> 3; j = k & 7;
#pragma unroll
      for (int i = 0; i < 4; ++i) {
        int d = 4 * d4b + i, t = d >> 4, lnw = d & 15;
        *(unsigned*)&sXT[(t * 64 + qs * 16 + lnw) * 8 + j] =
            (unsigned)f2bf(p0[i]) | ((unsigned)f2bf(p1[i]) << 16);
      }
    }
    __syncthreads();
    if (it + 32 < L) {  // prefetch next chunk while MFMAs run
      const float* Xn = X + (size_t)(it + 32) * D;
      pA0 = *(const float4*)(Xn + (size_t)(2 * k2a) * D + 4 * d4a);
      pA1 = *(const float4*)(Xn + (size_t)(2 * k2a + 1) * D + 4 * d4a);
      pB0 = *(const float4*)(Xn + (size_t)(2 * k2b) * D + 4 * d4b);
      pB1 = *(const float4*)(Xn + (size_t)(2 * k2b + 1) * D + 4 * d4b);
    }
    bf16x8 af[2], bfr[2];
#pragma unroll
    for (int rt = 0; rt < 2; ++rt)
      af[rt] = *(const bf16x8*)&sXT[((2 * wv + rt) * 64 + lane) * 8];
#pragma unroll
    for (int ct = 0; ct < 2; ++ct)
      bfr[ct] = *(const bf16x8*)&sXT[((2 * cs + ct) * 64 + lane) * 8];
#pragma unroll
    for (int rt = 0; rt < 2; ++rt)
#pragma unroll
      for (int ct = 0; ct < 2; ++ct)
        acc[rt][ct] = __builtin_amdgcn_mfma_f32_16x16x32_bf16(
            af[rt], bfr[ct], acc[rt][ct], 0, 0, 0);
  }

  // epilogue: single bf16 rounding from fp32 accumulators
  unsigned short* GG = gram + (size_t)g * (D * D);
#pragma unroll
  for (int rt = 0; rt < 2; ++rt)
#pragma unroll
    for (int ct = 0; ct < 2; ++ct)
#pragma unroll
      for (int r = 0; r < 4; ++r)
        GG[(size_t)(32 * wv + 16 * rt + quad * 4 + r) * D + 32 * cs + 16 * ct +
           ln] = f2bf(acc[rt][ct][r]);
}

// ---------------------------------------------------------------------------
// Fused main (UNCHANGED from R4). Block = 512 thr (8 waves) = 128 rows.
// ---------------------------------------------------------------------------
__global__ __launch_bounds__(512, 2) void fused_kernel3(
    const float* __restrict__ feats, const unsigned short* __restrict__ gram,
    const unsigned short* __restrict__ w2, float* __restrict__ out, int L) {
  const int tiles = L >> 7;  // blocks per graph
  const int gi = blockIdx.x / tiles;
  const int row0 = (blockIdx.x - gi * tiles) << 7;
  const float* __restrict__ A = feats + ((size_t)gi * L + row0) * D;
  const unsigned short* __restrict__ G = gram + (size_t)(gi ^ 1) * (D * D);
  float* __restrict__ O = out + ((size_t)gi * L + row0) * D;

  __shared__ __align__(16) unsigned short sAf[16384];  // ((kc*8+rt)*64+lane)*8
  __shared__ __align__(16) unsigned short sVf[16384];
  __shared__ __align__(16) unsigned short sBf[16384];

  const int tid = threadIdx.x;
  const int wv = tid >> 6, lane = tid & 63, quad = lane >> 4, ln = lane & 15;

  // stage A (fp32 -> bf16, frag order): 4096 float4 tasks, 8/thread
#pragma unroll
  for (int v = 0; v < 8; ++v) {
    int idx = tid + v * 512;
    int r = idx >> 5, c4 = idx & 31;
    float4 t = *(const float4*)(A + (size_t)r * D + c4 * 4);
    int kc = c4 >> 3, qd = (c4 & 7) >> 1, j0 = (c4 & 1) * 4;
    int rt = r >> 4, lnw = r & 15;
    uint2 pk;
    pk.x = (unsigned)f2bf(t.x) | ((unsigned)f2bf(t.y) << 16);
    pk.y = (unsigned)f2bf(t.z) | ((unsigned)f2bf(t.w) << 16);
    *(uint2*)&sAf[((kc * 8 + rt) * 64 + qd * 16 + lnw) * 8 + j0] = pk;
  }
  // stage Gram (bf16 frag order): 2048 uint4 tasks, 4/thread
#pragma unroll
  for (int v = 0; v < 4; ++v) {
    int idx = tid + v * 512;
    int r = idx >> 4, c16 = idx & 15;
    uint4 t = *(const uint4*)(G + (size_t)r * D + c16 * 8);
    int kc = c16 >> 2, qd = c16 & 3, tb = r >> 4, lnw = r & 15;
    *(uint4*)&sBf[((kc * 8 + tb) * 64 + qd * 16 + lnw) * 8] = t;
  }
  __syncthreads();

  // ---- phase 1: V2 = A * Gram ----
  f32x4 acc1[8];
#pragma unroll
  for (int ct = 0; ct < 8; ++ct) acc1[ct] = (f32x4)(0.f);
#pragma unroll
  for (int kc = 0; kc < 4; ++kc) {
    bf16x8 af = *(const bf16x8*)&sAf[((kc * 8 + wv) * 64 + lane) * 8];
#pragma unroll
    for (int ct = 0; ct < 8; ++ct) {
      bf16x8 bfr = *(const bf16x8*)&sBf[((kc * 8 + ct) * 64 + lane) * 8];
      acc1[ct] = __builtin_amdgcn_mfma_f32_16x16x32_bf16(af, bfr, acc1[ct], 0, 0, 0);
    }
  }
  // park V2 (C-layout -> A-frag order), rows stay within this wave's tile
#pragma unroll
  for (int ct = 0; ct < 8; ++ct)
#pragma unroll
    for (int r = 0; r < 4; ++r) {
      int col = ct * 16 + ln;
      int kc_t = col >> 5, q_t = (col >> 3) & 3, j_t = col & 7;
      sVf[((kc_t * 8 + wv) * 64 + q_t * 16 + quad * 4 + r) * 8 + j_t] =
          f2bf(acc1[ct][r]);
    }
  __syncthreads();

  // stage W2 into sBf (frag order)
#pragma unroll
  for (int v = 0; v < 4; ++v) {
    int idx = tid + v * 512;
    int r = idx >> 4, c16 = idx & 15;
    uint4 t = *(const uint4*)(w2 + (size_t)r * D + c16 * 8);
    int kc = c16 >> 2, qd = c16 & 3, tb = r >> 4, lnw = r & 15;
    *(uint4*)&sBf[((kc * 8 + tb) * 64 + qd * 16 + lnw) * 8] = t;
  }
  __syncthreads();

  // ---- phase 2: three GEMMs vs W2 ----
  f32x4 an[8], s1[8], s2[8];
#pragma unroll
  for (int ct = 0; ct < 8; ++ct) {
    an[ct] = (f32x4)(0.f);
    s1[ct] = (f32x4)(0.f);
    s2[ct] = (f32x4)(0.f);
  }
#pragma unroll
  for (int dc = 0; dc < 4; ++dc) {
    uint4 ua = *(const uint4*)&sAf[((dc * 8 + wv) * 64 + lane) * 8];
    uint4 uv = *(const uint4*)&sVf[((dc * 8 + wv) * 64 + lane) * 8];
    U4H8 fx2, faa, fvv;
    const unsigned* uap = &ua.x;
    const unsigned* uvp = &uv.x;
#pragma unroll
    for (int w = 0; w < 4; ++w) {
      float a0 = asf(uap[w] << 16), a1 = asf(uap[w] & 0xFFFF0000u);
      float v0 = asf(uvp[w] << 16), v1 = asf(uvp[w] & 0xFFFF0000u);
      (&fx2.u.x)[w] = __builtin_amdgcn_perm(asu(a1 * v1), asu(a0 * v0), 0x07060302u);
      (&faa.u.x)[w] = __builtin_amdgcn_perm(asu(a1 * a1), asu(a0 * a0), 0x07060302u);
      (&fvv.u.x)[w] = __builtin_amdgcn_perm(asu(v1 * v1), asu(v0 * v0), 0x07060302u);
    }
#pragma unroll
    for (int ct = 0; ct < 8; ++ct) {
      bf16x8 wf = *(const bf16x8*)&sBf[((dc * 8 + ct) * 64 + lane) * 8];
      an[ct] = __builtin_amdgcn_mfma_f32_16x16x32_bf16(fx2.h, wf, an[ct], 0, 0, 0);
      s1[ct] = __builtin_amdgcn_mfma_f32_16x16x32_bf16(faa.h, wf, s1[ct], 0, 0, 0);
      s2[ct] = __builtin_amdgcn_mfma_f32_16x16x32_bf16(fvv.h, wf, s2[ct], 0, 0, 0);
    }
  }

  // ---- epilogue ----
#pragma unroll
  for (int ct = 0; ct < 8; ++ct)
#pragma unroll
    for (int r = 0; r < 4; ++r) {
      float t = fmaxf(s1[ct][r] * s2[ct][r], 1e-16f);
      O[(size_t)(wv * 16 + quad * 4 + r) * D + ct * 16 + ln] =
          an[ct][r] * __builtin_amdgcn_rsqf(t);
    }
}

extern "C" void kernel_launch(void* const* d_in, const int* in_sizes, int n_in,
                              void* d_out, int out_size, void* d_ws, size_t ws_size,
                              hipStream_t stream) {
  const float* feats = (const float*)d_in[0];
  const float* w = (const float*)d_in[1];
  float* out = (float*)d_out;
  const int L = (in_sizes[0] / D) / GRAPHS;  // 2048

  unsigned short* gramBF = (unsigned short*)d_ws;                  // 2 MiB
  unsigned short* w2Buf = gramBF + (size_t)GRAPHS * D * D;         // 32 KiB

  hipLaunchKernelGGL(w2_kernel, dim3(D * D / 256), dim3(256), 0, stream, w, w2Buf);
  hipLaunchKernelGGL(gram_slab_kernel, dim3(GRAPHS * 4), dim3(256), 0, stream,
                     feats, gramBF, L);
  hipLaunchKernelGGL(fused_kernel3, dim3(GRAPHS * (L >> 7)), dim3(512), 0,
                     stream, feats, gramBF, w2Buf, out, L);
}

// Round 7
// 160.435 us; speedup vs baseline: 2.1454x; 1.3619x over previous
//
#include <hip/hip_runtime.h>
#include <math.h>

#define D 128
#define GRAPHS 64

typedef __attribute__((ext_vector_type(8))) short bf16x8;
typedef __attribute__((ext_vector_type(4))) float f32x4;

union U4H8 { uint4 u; bf16x8 h; };

__device__ __forceinline__ unsigned short f2bf(float f) {   // RNE
  union { float f; unsigned u; } v; v.f = f;
  unsigned r = v.u + 0x7fffu + ((v.u >> 16) & 1u);
  return (unsigned short)(r >> 16);
}
__device__ __forceinline__ unsigned asu(float f) {
  union { float f; unsigned u; } v; v.f = f; return v.u;
}
__device__ __forceinline__ float asf(unsigned u) {
  union { unsigned u; float f; } v; v.u = u; return v.f;
}

// ---------------------------------------------------------------------------
// Gram partials: grid = GRAPHS*KS blocks x 256 thr (4 waves). Block (g,sl):
// fp32-register XsT*Xs over chunk=L/KS rows (acc[2][8], 64 VGPR), K-chunks of
// 64 rows (32 KB/block in flight -> BW-saturated; feats read EXACTLY once
// chip-wide). bf16 partial written coalesced via LDS round-trip.
// ---------------------------------------------------------------------------
__global__ __launch_bounds__(256, 2) void gram_partial_kernel(
    const float* __restrict__ feats, unsigned short* __restrict__ partial,
    int L, int KS) {
  const int g = blockIdx.x / KS;
  const int sl = blockIdx.x - g * KS;
  const int chunk = L / KS;
  const float* __restrict__ X = feats + ((size_t)g * L + (size_t)sl * chunk) * D;

  __shared__ __align__(16) unsigned short smem[16384];  // 32 KB (stage uses 16)
  const int tid = threadIdx.x;
  const int wv = tid >> 6, lane = tid & 63, quad = lane >> 4, ln = lane & 15;

  f32x4 acc[2][8];
#pragma unroll
  for (int rt = 0; rt < 2; ++rt)
#pragma unroll
    for (int ct = 0; ct < 8; ++ct) acc[rt][ct] = (f32x4)(0.f);

  // 1024 pair-tasks (32 k-pairs x 32 d4) per 64-row chunk, 4 per thread
  int k2v[4], d4v[4];
#pragma unroll
  for (int v = 0; v < 4; ++v) {
    int tt = tid + v * 256;
    k2v[v] = tt & 31;
    d4v[v] = tt >> 5;
  }
  float4 pf[8];
#pragma unroll
  for (int v = 0; v < 4; ++v) {
    pf[2 * v] = *(const float4*)(X + (size_t)(2 * k2v[v]) * D + 4 * d4v[v]);
    pf[2 * v + 1] = *(const float4*)(X + (size_t)(2 * k2v[v] + 1) * D + 4 * d4v[v]);
  }

  for (int it = 0; it < chunk; it += 64) {
    __syncthreads();
#pragma unroll
    for (int v = 0; v < 4; ++v) {
      const float* p0 = (const float*)&pf[2 * v];
      const float* p1 = (const float*)&pf[2 * v + 1];
      int k = 2 * k2v[v];
      int ks = k >> 5, kk = k & 31, qs = kk >> 3, j = kk & 7;
#pragma unroll
      for (int i = 0; i < 4; ++i) {
        int d = 4 * d4v[v] + i, t = d >> 4, lnw = d & 15;
        *(unsigned*)&smem[((ks * 8 + t) * 64 + qs * 16 + lnw) * 8 + j] =
            (unsigned)f2bf(p0[i]) | ((unsigned)f2bf(p1[i]) << 16);
      }
    }
    __syncthreads();
    if (it + 64 < chunk) {  // prefetch next 64-row chunk
      const float* Xn = X + (size_t)(it + 64) * D;
#pragma unroll
      for (int v = 0; v < 4; ++v) {
        pf[2 * v] = *(const float4*)(Xn + (size_t)(2 * k2v[v]) * D + 4 * d4v[v]);
        pf[2 * v + 1] =
            *(const float4*)(Xn + (size_t)(2 * k2v[v] + 1) * D + 4 * d4v[v]);
      }
    }
#pragma unroll
    for (int ks = 0; ks < 2; ++ks) {
      bf16x8 af[2], bfr[8];
      af[0] = *(const bf16x8*)&smem[((ks * 8 + 2 * wv) * 64 + lane) * 8];
      af[1] = *(const bf16x8*)&smem[((ks * 8 + 2 * wv + 1) * 64 + lane) * 8];
#pragma unroll
      for (int ct = 0; ct < 8; ++ct)
        bfr[ct] = *(const bf16x8*)&smem[((ks * 8 + ct) * 64 + lane) * 8];
#pragma unroll
      for (int rt = 0; rt < 2; ++rt)
#pragma unroll
        for (int ct = 0; ct < 8; ++ct)
          acc[rt][ct] = __builtin_amdgcn_mfma_f32_16x16x32_bf16(
              af[rt], bfr[ct], acc[rt][ct], 0, 0, 0);
    }
  }

  // park C-layout -> row-major bf16 in LDS, then coalesced writeout
  __syncthreads();
#pragma unroll
  for (int rt = 0; rt < 2; ++rt)
#pragma unroll
    for (int ct = 0; ct < 8; ++ct)
#pragma unroll
      for (int r = 0; r < 4; ++r)
        smem[(32 * wv + 16 * rt + quad * 4 + r) * 128 + 16 * ct + ln] =
            f2bf(acc[rt][ct][r]);
  __syncthreads();
  unsigned short* P = partial + ((size_t)sl * GRAPHS + g) * (D * D);
#pragma unroll
  for (int v = 0; v < 8; ++v) {
    int idx = tid + v * 256;
    *(uint4*)&P[(size_t)idx * 8] = *(uint4*)&smem[idx * 8];
  }
}

// ---------------------------------------------------------------------------
// Reduce KS bf16 partials -> bf16 gram (blocks 0..511) + w2 (blocks 512..519).
// ---------------------------------------------------------------------------
__global__ __launch_bounds__(256) void reduce_w2_kernel(
    const unsigned short* __restrict__ partial, unsigned short* __restrict__ gram,
    const float* __restrict__ w, unsigned short* __restrict__ w2, int KS) {
  const int bid = blockIdx.x;
  if (bid < 512) {
    int idx = bid * 256 + threadIdx.x;  // each handles 8 elems
    int e8 = idx * 8;
    int g = e8 >> 14, e = e8 & (D * D - 1);
    float s[8];
#pragma unroll
    for (int i = 0; i < 8; ++i) s[i] = 0.f;
    for (int sl = 0; sl < KS; ++sl) {
      uint4 t = *(const uint4*)&partial[((size_t)sl * GRAPHS + g) * (D * D) + e];
      const unsigned* tp = &t.x;
#pragma unroll
      for (int q = 0; q < 4; ++q) {
        s[2 * q] += asf(tp[q] << 16);
        s[2 * q + 1] += asf(tp[q] & 0xFFFF0000u);
      }
    }
    uint4 o;
    o.x = (unsigned)f2bf(s[0]) | ((unsigned)f2bf(s[1]) << 16);
    o.y = (unsigned)f2bf(s[2]) | ((unsigned)f2bf(s[3]) << 16);
    o.z = (unsigned)f2bf(s[4]) | ((unsigned)f2bf(s[5]) << 16);
    o.w = (unsigned)f2bf(s[6]) | ((unsigned)f2bf(s[7]) << 16);
    *(uint4*)&gram[(size_t)g * (D * D) + e] = o;
  } else {
    int idx = (bid - 512) * 256 + threadIdx.x;  // 2048 thr x 8 elems
    const float* src = w + (size_t)idx * 8;
    float4 a = *(const float4*)src;
    float4 b = *(const float4*)(src + 4);
    uint4 o;
    o.x = (unsigned)f2bf(a.x * a.x) | ((unsigned)f2bf(a.y * a.y) << 16);
    o.y = (unsigned)f2bf(a.z * a.z) | ((unsigned)f2bf(a.w * a.w) << 16);
    o.z = (unsigned)f2bf(b.x * b.x) | ((unsigned)f2bf(b.y * b.y) << 16);
    o.w = (unsigned)f2bf(b.z * b.z) | ((unsigned)f2bf(b.w * b.w) << 16);
    *(uint4*)&w2[(size_t)idx * 8] = o;
  }
}

// ---------------------------------------------------------------------------
// Fused main. grid = GRAPHS*(L/64) = 2048 blocks x 512 thr (8 waves).
// Block = 64 rows; wave (rowg=wv>>1, colg=wv&1) = 16 rows x 64 cols.
// Phase-2 accs = 48 VGPR -> fits 128-VGPR cap (launch_bounds(512,4)):
// 4 waves/SIMD, 2 blocks/CU. Repack redundancy 2x (occupancy > dedup, per R5).
// ---------------------------------------------------------------------------
__global__ __launch_bounds__(512, 4) void fused_kernel4(
    const float* __restrict__ feats, const unsigned short* __restrict__ gram,
    const unsigned short* __restrict__ w2, float* __restrict__ out, int L) {
  const int tiles = L >> 6;
  const int gi = blockIdx.x / tiles;
  const int row0 = (blockIdx.x - gi * tiles) << 6;
  const float* __restrict__ A = feats + ((size_t)gi * L + row0) * D;
  const unsigned short* __restrict__ G = gram + (size_t)(gi ^ 1) * (D * D);
  float* __restrict__ O = out + ((size_t)gi * L + row0) * D;

  __shared__ __align__(16) unsigned short sAf[8192];   // ((kc*4+rt)*64+lane)*8
  __shared__ __align__(16) unsigned short sVf[8192];
  __shared__ __align__(16) unsigned short sBf[16384];  // ((kc*8+tb)*64+lane)*8

  const int tid = threadIdx.x;
  const int wv = tid >> 6, lane = tid & 63, quad = lane >> 4, ln = lane & 15;
  const int rowg = wv >> 1, colg = wv & 1;

  // stage A (fp32 -> bf16, frag order): 2048 float4 tasks, 4/thread
#pragma unroll
  for (int v = 0; v < 4; ++v) {
    int idx = tid + v * 512;
    int r = idx >> 5, c4 = idx & 31;
    float4 t = *(const float4*)(A + (size_t)r * D + c4 * 4);
    int kc = c4 >> 3, qd = (c4 & 7) >> 1, j0 = (c4 & 1) * 4;
    int rt = r >> 4, lnw = r & 15;
    uint2 pk;
    pk.x = (unsigned)f2bf(t.x) | ((unsigned)f2bf(t.y) << 16);
    pk.y = (unsigned)f2bf(t.z) | ((unsigned)f2bf(t.w) << 16);
    *(uint2*)&sAf[((kc * 4 + rt) * 64 + qd * 16 + lnw) * 8 + j0] = pk;
  }
  // stage Gram (bf16 frag order): 2048 uint4 tasks, 4/thread
#pragma unroll
  for (int v = 0; v < 4; ++v) {
    int idx = tid + v * 512;
    int r = idx >> 4, c16 = idx & 15;
    uint4 t = *(const uint4*)(G + (size_t)r * D + c16 * 8);
    int kc = c16 >> 2, qd = c16 & 3, tb = r >> 4, lnw = r & 15;
    *(uint4*)&sBf[((kc * 8 + tb) * 64 + qd * 16 + lnw) * 8] = t;
  }
  __syncthreads();

  // ---- phase 1: V2 = A * Gram (wave: 16 rows x 64 cols) ----
  f32x4 acc1[4];
#pragma unroll
  for (int c = 0; c < 4; ++c) acc1[c] = (f32x4)(0.f);
#pragma unroll
  for (int kc = 0; kc < 4; ++kc) {
    bf16x8 af = *(const bf16x8*)&sAf[((kc * 4 + rowg) * 64 + lane) * 8];
#pragma unroll
    for (int c = 0; c < 4; ++c) {
      int ct = colg * 4 + c;
      bf16x8 bfr = *(const bf16x8*)&sBf[((kc * 8 + ct) * 64 + lane) * 8];
      acc1[c] = __builtin_amdgcn_mfma_f32_16x16x32_bf16(af, bfr, acc1[c], 0, 0, 0);
    }
  }
  // park V2 (C-layout -> A-frag order)
#pragma unroll
  for (int c = 0; c < 4; ++c)
#pragma unroll
    for (int r = 0; r < 4; ++r) {
      int col = (colg * 4 + c) * 16 + ln;
      int kc_t = col >> 5, q_t = (col >> 3) & 3, j_t = col & 7;
      sVf[((kc_t * 4 + rowg) * 64 + q_t * 16 + quad * 4 + r) * 8 + j_t] =
          f2bf(acc1[c][r]);
    }
  __syncthreads();

  // stage W2 into sBf (frag order)
#pragma unroll
  for (int v = 0; v < 4; ++v) {
    int idx = tid + v * 512;
    int r = idx >> 4, c16 = idx & 15;
    uint4 t = *(const uint4*)(w2 + (size_t)r * D + c16 * 8);
    int kc = c16 >> 2, qd = c16 & 3, tb = r >> 4, lnw = r & 15;
    *(uint4*)&sBf[((kc * 8 + tb) * 64 + qd * 16 + lnw) * 8] = t;
  }
  __syncthreads();

  // ---- phase 2: three GEMMs vs W2 ----
  f32x4 an[4], s1[4], s2[4];
#pragma unroll
  for (int c = 0; c < 4; ++c) {
    an[c] = (f32x4)(0.f);
    s1[c] = (f32x4)(0.f);
    s2[c] = (f32x4)(0.f);
  }
#pragma unroll
  for (int dc = 0; dc < 4; ++dc) {
    uint4 ua = *(const uint4*)&sAf[((dc * 4 + rowg) * 64 + lane) * 8];
    uint4 uv = *(const uint4*)&sVf[((dc * 4 + rowg) * 64 + lane) * 8];
    U4H8 fx2, faa, fvv;
    const unsigned* uap = &ua.x;
    const unsigned* uvp = &uv.x;
#pragma unroll
    for (int q = 0; q < 4; ++q) {
      float a0 = asf(uap[q] << 16), a1 = asf(uap[q] & 0xFFFF0000u);
      float v0 = asf(uvp[q] << 16), v1 = asf(uvp[q] & 0xFFFF0000u);
      (&fx2.u.x)[q] = __builtin_amdgcn_perm(asu(a1 * v1), asu(a0 * v0), 0x07060302u);
      (&faa.u.x)[q] = __builtin_amdgcn_perm(asu(a1 * a1), asu(a0 * a0), 0x07060302u);
      (&fvv.u.x)[q] = __builtin_amdgcn_perm(asu(v1 * v1), asu(v0 * v0), 0x07060302u);
    }
#pragma unroll
    for (int c = 0; c < 4; ++c) {
      int ct = colg * 4 + c;
      bf16x8 wf = *(const bf16x8*)&sBf[((dc * 8 + ct) * 64 + lane) * 8];
      an[c] = __builtin_amdgcn_mfma_f32_16x16x32_bf16(fx2.h, wf, an[c], 0, 0, 0);
      s1[c] = __builtin_amdgcn_mfma_f32_16x16x32_bf16(faa.h, wf, s1[c], 0, 0, 0);
      s2[c] = __builtin_amdgcn_mfma_f32_16x16x32_bf16(fvv.h, wf, s2[c], 0, 0, 0);
    }
  }

  // ---- epilogue ----
#pragma unroll
  for (int c = 0; c < 4; ++c)
#pragma unroll
    for (int r = 0; r < 4; ++r) {
      float t = fmaxf(s1[c][r] * s2[c][r], 1e-16f);
      O[(size_t)(rowg * 16 + quad * 4 + r) * D + (colg * 4 + c) * 16 + ln] =
          an[c][r] * __builtin_amdgcn_rsqf(t);
    }
}

extern "C" void kernel_launch(void* const* d_in, const int* in_sizes, int n_in,
                              void* d_out, int out_size, void* d_ws, size_t ws_size,
                              hipStream_t stream) {
  const float* feats = (const float*)d_in[0];
  const float* w = (const float*)d_in[1];
  float* out = (float*)d_out;
  const int L = (in_sizes[0] / D) / GRAPHS;  // 2048

  const size_t partSlice = (size_t)GRAPHS * D * D * sizeof(unsigned short);  // 2 MiB
  const size_t gramB = partSlice;                                            // 2 MiB
  const size_t w2B = (size_t)D * D * sizeof(unsigned short);                 // 32 KiB
  int KS = 4;
  while (KS > 1 && (size_t)KS * partSlice + gramB + w2B > ws_size) KS >>= 1;

  unsigned short* partialBuf = (unsigned short*)d_ws;
  unsigned short* gramBuf = partialBuf + (size_t)KS * GRAPHS * D * D;
  unsigned short* w2Buf = gramBuf + (size_t)GRAPHS * D * D;

  hipLaunchKernelGGL(gram_partial_kernel, dim3(GRAPHS * KS), dim3(256), 0,
                     stream, feats, partialBuf, L, KS);
  hipLaunchKernelGGL(reduce_w2_kernel, dim3(520), dim3(256), 0, stream,
                     partialBuf, gramBuf, w, w2Buf, KS);
  hipLaunchKernelGGL(fused_kernel4, dim3(GRAPHS * (L >> 6)), dim3(512), 0,
                     stream, feats, gramBuf, w2Buf, out, L);
}